// Round 6
// baseline (141.427 us; speedup 1.0000x reference)
//
#include <hip/hip_runtime.h>
#include <math.h>

// Problem constants (match reference)
#define Kp 128
#define Tn 64
#define Dn 128
#define Hn 512
#define RS 136   // ushort row stride for bf16 E rows: 272 B (16B-aligned), +4 banks/row

typedef __attribute__((ext_vector_type(8))) short short8;   // 8 bf16 = 4 VGPRs (MFMA A/B frag)
typedef __attribute__((ext_vector_type(4))) float f32x4;    // MFMA C/D frag

// Two blocks per particle: hf=0/1 each compute the full (cheap) Gram/argmax
// phase redundantly, then split the MLP weight stream: layer 1 by columns
// (256 KB W1 each), layer 2 by the inner j over the block's OWN h-half
// (128 KB W2 each) -> no h exchange; one 128-float partial-E exchange via
// a device-scope release/acquire flag in d_ws.
__global__ __launch_bounds__(256, 1) void ep_kernel(
    const int*   __restrict__ Nptr,    // [1]
    const int*   __restrict__ leaf,    // K x 64 (int32)
    const float* __restrict__ emb,     // K x 64 x 128
    const float* __restrict__ W1,      // 256 x 512
    const float* __restrict__ b1,      // 512
    const float* __restrict__ W2,      // 512 x 128
    const float* __restrict__ b2,      // 128
    const float* __restrict__ gum,     // K x 4096
    const float* __restrict__ u1,      // K
    const float* __restrict__ u2,      // K
    float* __restrict__ wsE,           // ws: partial-E [Kp][Dn]
    int*   __restrict__ wsFlag,        // ws: flags [Kp]
    float* __restrict__ out)           // 17152 floats
{
    const int k    = blockIdx.x >> 1;   // particle
    const int hf   = blockIdx.x & 1;    // MLP half
    const int tid  = threadIdx.x;
    const int lane = tid & 63;
    const int wid  = tid >> 6;

    __shared__ unsigned short EH[Tn * RS];   // bf16 hi of embeddings, 17408 B
    __shared__ unsigned short EL[Tn * RS];   // bf16 lo residual, 17408 B
    __shared__ float xs[256];        // concat(child1, child2)
    __shared__ float hsh[256];       // this block's h-half
    __shared__ float buf[1056];      // MLP partials (L1: 4x260, L2: 8x132)
    __shared__ float nI[Tn];         // squared norms (diag of Gram)
    __shared__ float sBest[4]; __shared__ int sIdx[4]; __shared__ float sW[4];
    __shared__ float sSum[4];
    __shared__ float sD1[4]; __shared__ float sD2[4];
    __shared__ int   sOnes;
    __shared__ int   fIdx; __shared__ float fW;
    __shared__ float embs[Dn];

    // wave -> 2x2 block of 16x16 G-tiles: wid 0..3 -> (itp,jtp)
    const int itp  = wid >> 1;
    const int jtp  = wid & 1;
    const int lrow = lane & 15;
    const int lq   = lane >> 4;

    // --- ones count (wave 0) ---
    if (tid < 64) {
        unsigned long long m = __ballot(leaf[k * Tn + tid] == 1);
        if (tid == 0) sOnes = __popcll(m);
    }

    // --- EARLY global loads: embeddings (8 f4) + this thread's 16 gumbel entries ---
    float4 ev[8];
    {
        const float4* src = (const float4*)(emb + (size_t)k * Tn * Dn);
        #pragma unroll
        for (int it = 0; it < 8; ++it) ev[it] = src[tid + it * 256];
    }
    float gv[16];
    {
        const float* gk = gum + (size_t)k * (Tn * Tn);
        #pragma unroll
        for (int a = 0; a < 2; ++a)
            #pragma unroll
            for (int b = 0; b < 2; ++b) {
                int it = 2 * itp + a, jt = 2 * jtp + b;
                int col = jt * 16 + lrow;
                #pragma unroll
                for (int r = 0; r < 4; ++r) {
                    int row = it * 16 + lq * 4 + r;
                    gv[(a * 2 + b) * 4 + r] = gk[row * Tn + col];
                }
            }
    }

    // --- pack split-bf16 embeddings into LDS (e = hi + lo, |err| <= 2^-16|e|) ---
    #pragma unroll
    for (int it = 0; it < 8; ++it) {
        int f4 = tid + it * 256;
        int i  = f4 >> 5;
        int d0 = (f4 & 31) << 2;
        float4 v = ev[it];
        unsigned short hx = __float_as_uint(v.x) >> 16, hy = __float_as_uint(v.y) >> 16,
                       hz = __float_as_uint(v.z) >> 16, hw = __float_as_uint(v.w) >> 16;
        float rx = v.x - __uint_as_float((unsigned int)hx << 16);
        float ry = v.y - __uint_as_float((unsigned int)hy << 16);
        float rz = v.z - __uint_as_float((unsigned int)hz << 16);
        float rw = v.w - __uint_as_float((unsigned int)hw << 16);
        unsigned short lx = __float_as_uint(rx) >> 16, ly = __float_as_uint(ry) >> 16,
                       lz = __float_as_uint(rz) >> 16, lw = __float_as_uint(rw) >> 16;
        *(ushort4*)&EH[i * RS + d0] = make_ushort4(hx, hy, hz, hw);
        *(ushort4*)&EL[i * RS + d0] = make_ushort4(lx, ly, lz, lw);
    }
    __syncthreads();

    // --- MFMA Gram: G = Ehi.Ehi^T + Ehi.Elo^T + Elo.Ehi^T (fp32-accurate) ---
    f32x4 acc[2][2] = {};
    const int ka = lq * 8;
    #pragma unroll
    for (int ks = 0; ks < 4; ++ks) {
        int kb  = ks * 32 + ka;
        int ra0 = ((2 * itp + 0) * 16 + lrow) * RS + kb;
        int ra1 = ra0 + 16 * RS;
        int rb0 = ((2 * jtp + 0) * 16 + lrow) * RS + kb;
        int rb1 = rb0 + 16 * RS;
        short8 ah0 = *(const short8*)&EH[ra0], ah1 = *(const short8*)&EH[ra1];
        short8 al0 = *(const short8*)&EL[ra0], al1 = *(const short8*)&EL[ra1];
        short8 bh0 = *(const short8*)&EH[rb0], bh1 = *(const short8*)&EH[rb1];
        short8 bl0 = *(const short8*)&EL[rb0], bl1 = *(const short8*)&EL[rb1];
        acc[0][0] = __builtin_amdgcn_mfma_f32_16x16x32_bf16(ah0, bh0, acc[0][0], 0, 0, 0);
        acc[0][1] = __builtin_amdgcn_mfma_f32_16x16x32_bf16(ah0, bh1, acc[0][1], 0, 0, 0);
        acc[1][0] = __builtin_amdgcn_mfma_f32_16x16x32_bf16(ah1, bh0, acc[1][0], 0, 0, 0);
        acc[1][1] = __builtin_amdgcn_mfma_f32_16x16x32_bf16(ah1, bh1, acc[1][1], 0, 0, 0);
        acc[0][0] = __builtin_amdgcn_mfma_f32_16x16x32_bf16(ah0, bl0, acc[0][0], 0, 0, 0);
        acc[0][1] = __builtin_amdgcn_mfma_f32_16x16x32_bf16(ah0, bl1, acc[0][1], 0, 0, 0);
        acc[1][0] = __builtin_amdgcn_mfma_f32_16x16x32_bf16(ah1, bl0, acc[1][0], 0, 0, 0);
        acc[1][1] = __builtin_amdgcn_mfma_f32_16x16x32_bf16(ah1, bl1, acc[1][1], 0, 0, 0);
        acc[0][0] = __builtin_amdgcn_mfma_f32_16x16x32_bf16(al0, bh0, acc[0][0], 0, 0, 0);
        acc[0][1] = __builtin_amdgcn_mfma_f32_16x16x32_bf16(al0, bh1, acc[0][1], 0, 0, 0);
        acc[1][0] = __builtin_amdgcn_mfma_f32_16x16x32_bf16(al1, bh0, acc[1][0], 0, 0, 0);
        acc[1][1] = __builtin_amdgcn_mfma_f32_16x16x32_bf16(al1, bh1, acc[1][1], 0, 0, 0);
    }

    // --- norms from diagonal tiles ---
    if (itp == jtp) {
        #pragma unroll
        for (int a = 0; a < 2; ++a) {
            if ((lrow >> 2) == lq) {
                int c = lrow;
                int t = 2 * itp + a;
                f32x4 v = acc[a][a];
                int   s = c & 3;
                float val = (s == 0) ? v.x : (s == 1) ? v.y : (s == 2) ? v.z : v.w;
                nI[t * 16 + c] = val;
            }
        }
    }
    __syncthreads();

    // --- merge log-weights + argmax(w+g) + direct expsum ---
    float es = 0.0f, best = -INFINITY, bestW = 0.0f;
    int   bestIdx = 0;
    #pragma unroll
    for (int a = 0; a < 2; ++a)
        #pragma unroll
        for (int b = 0; b < 2; ++b) {
            int it = 2 * itp + a, jt = 2 * jtp + b;
            int col = jt * 16 + lrow;
            float njc = nI[col];
            f32x4 v = acc[a][b];
            float gvals[4] = {v.x, v.y, v.z, v.w};
            #pragma unroll
            for (int r = 0; r < 4; ++r) {
                int row = it * 16 + lq * 4 + r;
                float pd2 = nI[row] + njc - 2.0f * gvals[r];
                pd2 = fmaxf(pd2, 0.0f) + 1e-12f;
                float wv = (row == col) ? -INFINITY : -sqrtf(pd2);
                es += expf(wv);
                float wg = wv + gv[(a * 2 + b) * 4 + r];
                int idx = row * Tn + col;
                if (wg > best || (wg == best && idx < bestIdx)) {
                    best = wg; bestIdx = idx; bestW = wv;
                }
            }
        }

    #pragma unroll
    for (int off = 32; off > 0; off >>= 1) {
        float ob = __shfl_down(best, off);
        int   oi = __shfl_down(bestIdx, off);
        float ow = __shfl_down(bestW, off);
        float oe = __shfl_down(es, off);
        if (ob > best || (ob == best && oi < bestIdx)) { best = ob; bestIdx = oi; bestW = ow; }
        es += oe;
    }
    if (lane == 0) { sBest[wid] = best; sIdx[wid] = bestIdx; sW[wid] = bestW; sSum[wid] = es; }
    __syncthreads();
    if (tid == 0) {
        best = sBest[0]; bestIdx = sIdx[0]; bestW = sW[0];
        #pragma unroll
        for (int q = 1; q < 4; ++q) {
            if (sBest[q] > best || (sBest[q] == best && sIdx[q] < bestIdx)) {
                best = sBest[q]; bestIdx = sIdx[q]; bestW = sW[q];
            }
        }
        fIdx = bestIdx; fW = bestW;
    }
    __syncthreads();

    const int i1 = fIdx >> 6;
    const int i2 = fIdx & 63;

    // --- gather children into xs = concat(c1, c2), reconstructed hi+lo ---
    {
        int d  = tid & 127;
        int ii = (tid < 128) ? i1 : i2;
        float hi = __uint_as_float((unsigned int)EH[ii * RS + d] << 16);
        float lo = __uint_as_float((unsigned int)EL[ii * RS + d] << 16);
        xs[tid] = hi + lo;
    }
    __syncthreads();

    // --- MLP layer 1 (this block's 256-column half): thread owns 4 cols, 4-way i-split ---
    {
        const int jloc = 4 * (tid & 63);           // 0..252 within half
        const int ih   = tid >> 6;                 // 0..3
        const float* W1r = W1 + (size_t)hf * 256 + jloc;
        float4 a = {0, 0, 0, 0};
        const int ib = ih * 64;
        #pragma unroll 4
        for (int i = ib; i < ib + 64; i += 4) {
            float4 x  = *(const float4*)&xs[i];
            float4 w0 = *(const float4*)&W1r[(size_t)(i + 0) * Hn];
            float4 w1 = *(const float4*)&W1r[(size_t)(i + 1) * Hn];
            float4 w2 = *(const float4*)&W1r[(size_t)(i + 2) * Hn];
            float4 w3 = *(const float4*)&W1r[(size_t)(i + 3) * Hn];
            a.x += x.x * w0.x + x.y * w1.x + x.z * w2.x + x.w * w3.x;
            a.y += x.x * w0.y + x.y * w1.y + x.z * w2.y + x.w * w3.y;
            a.z += x.x * w0.z + x.y * w1.z + x.z * w2.z + x.w * w3.z;
            a.w += x.x * w0.w + x.y * w1.w + x.z * w2.w + x.w * w3.w;
        }
        *(float4*)&buf[ih * 260 + jloc] = a;   // stride 260: %32==4 -> conflict-free combine
    }
    __syncthreads();
    hsh[tid] = fmaxf(b1[hf * 256 + tid] + buf[tid] + buf[260 + tid]
                     + buf[520 + tid] + buf[780 + tid], 0.0f);
    __syncthreads();

    // --- MLP layer 2 over OWN h-half: thread owns 4 d-cols, 8-way j-split ---
    {
        const int jh  = tid >> 5;          // 0..7
        const int dd4 = 4 * (tid & 31);    // 0..124
        float4 a = {0, 0, 0, 0};
        const int jb = jh * 32;
        #pragma unroll 4
        for (int j = jb; j < jb + 32; j += 4) {
            float4 h4 = *(const float4*)&hsh[j];
            const size_t rg = (size_t)(hf * 256 + j);
            float4 w0 = *(const float4*)&W2[(rg + 0) * Dn + dd4];
            float4 w1 = *(const float4*)&W2[(rg + 1) * Dn + dd4];
            float4 w2 = *(const float4*)&W2[(rg + 2) * Dn + dd4];
            float4 w3 = *(const float4*)&W2[(rg + 3) * Dn + dd4];
            a.x += h4.x * w0.x + h4.y * w1.x + h4.z * w2.x + h4.w * w3.x;
            a.y += h4.x * w0.y + h4.y * w1.y + h4.z * w2.y + h4.w * w3.y;
            a.z += h4.x * w0.z + h4.y * w1.z + h4.z * w2.z + h4.w * w3.z;
            a.w += h4.x * w0.w + h4.y * w1.w + h4.z * w2.w + h4.w * w3.w;
        }
        *(float4*)&buf[jh * 132 + dd4] = a;    // stride 132: %32==4 -> conflict-free combine
    }
    __syncthreads();

    if (hf == 1) {
        // publish partial E, release flag, exit
        if (tid < 128) {
            float ep = 0.0f;
            #pragma unroll
            for (int p = 0; p < 8; ++p) ep += buf[p * 132 + tid];
            wsE[k * Dn + tid] = ep;
        }
        __syncthreads();
        __threadfence();
        if (tid == 0) __hip_atomic_store(&wsFlag[k], 1, __ATOMIC_RELEASE, __HIP_MEMORY_SCOPE_AGENT);
        return;
    }

    // --- hf == 0: combine own partial with partner's, then epilogue ---
    float myEp = 0.0f;
    if (tid < 128) {
        #pragma unroll
        for (int p = 0; p < 8; ++p) myEp += buf[p * 132 + tid];
    }
    if (tid == 0) {
        while (__hip_atomic_load(&wsFlag[k], __ATOMIC_ACQUIRE, __HIP_MEMORY_SCOPE_AGENT) != 1) {}
    }
    __syncthreads();   // all threads wait until partner's E is visible

    if (tid < 128) {
        float e = myEp + wsE[k * Dn + tid] + b2[tid];
        embs[tid] = e;
        out[4 * Kp + k * Dn + tid] = e;   // embedding output at offset 512
    }
    __syncthreads();

    // --- branch distances d1, d2 ---
    float v1 = 0.0f, v2 = 0.0f;
    if (tid < 128) {
        float e  = embs[tid];
        float q1 = xs[tid] - e;        v1 = q1 * q1;
        float q2 = xs[128 + tid] - e;  v2 = q2 * q2;
    }
    #pragma unroll
    for (int off = 32; off > 0; off >>= 1) {
        v1 += __shfl_down(v1, off);
        v2 += __shfl_down(v2, off);
    }
    if (lane == 0) { sD1[wid] = v1; sD2[wid] = v2; }
    __syncthreads();

    // --- scalar epilogue (thread 0) ---
    if (tid == 0) {
        float s1 = sD1[0] + sD1[1];
        float s2 = sD2[0] + sD2[1];
        float d1 = sqrtf(s1 + 1e-12f);
        float d2 = sqrtf(s2 + 1e-12f);
        float rate1 = 1.0f / (d1 + 1e-4f);
        float rate2 = 1.0f / (d2 + 1e-4f);
        float branch1 = -(1.0f / rate1) * logf(u1[k]);
        float branch2 = -(1.0f / rate2) * logf(u2[k]);
        float lbp1 = logf(rate1) - rate1 * branch1;
        float lbp2 = logf(rate2) - rate2 * branch2;
        float ssum = sSum[0] + sSum[1] + sSum[2] + sSum[3];
        float lse  = logf(ssum);                          // direct-sum logsumexp
        float lmp  = fW + 0.69314718055994531f - lse;     // + log(2)
        float lvp  = lmp + lbp1 + lbp2;
        int lc1 = leaf[k * Tn + i1];
        int lc2 = leaf[k * Tn + i2];
        int ones = sOnes - (lc1 == 1 ? 1 : 0) - (lc2 == 1 ? 1 : 0);
        float lvm = logf((float)(Nptr[0] - ones));

        out[k]                         = (float)i1;
        out[Kp + k]                    = (float)i2;
        out[2 * Kp + k]                = branch1;
        out[3 * Kp + k]                = branch2;
        out[4 * Kp + Kp * Dn + k]      = lvp;   // offset 16896
        out[4 * Kp + Kp * Dn + Kp + k] = lvm;   // offset 17024
    }
}

extern "C" void kernel_launch(void* const* d_in, const int* in_sizes, int n_in,
                              void* d_out, int out_size, void* d_ws, size_t ws_size,
                              hipStream_t stream) {
    const int*   Nptr = (const int*)  d_in[0];
    const int*   leaf = (const int*)  d_in[1];
    const float* emb  = (const float*)d_in[2];
    // d_in[3] log_felsensteins, d_in[4] site_positions: unused by reference
    const float* W1   = (const float*)d_in[5];
    const float* b1   = (const float*)d_in[6];
    const float* W2   = (const float*)d_in[7];
    const float* b2   = (const float*)d_in[8];
    const float* gum  = (const float*)d_in[9];
    const float* u1   = (const float*)d_in[10];
    const float* u2   = (const float*)d_in[11];
    float* out = (float*)d_out;

    float* wsE   = (float*)d_ws;                          // Kp*Dn floats (64 KB)
    int*   wsFlag = (int*)((char*)d_ws + Kp * Dn * sizeof(float));  // Kp ints
    // wsFlag is re-poisoned to 0xAA by the harness before every launch; the
    // release-store of 1 is the only transition the spin waits for.

    ep_kernel<<<2 * Kp, 256, 0, stream>>>(Nptr, leaf, emb, W1, b1, W2, b2, gum, u1, u2,
                                          wsE, wsFlag, out);
}

// Round 7
// 127.083 us; speedup vs baseline: 1.1129x; 1.1129x over previous
//
#include <hip/hip_runtime.h>
#include <math.h>

// Problem constants (match reference)
#define Kp 128
#define Tn 64
#define Dn 128
#define Hn 512
#define RS 136   // ushort row stride for bf16 E rows: 272 B (16B-aligned), +4 banks/row
#define NPRE 24  // W1 rows prefetched per thread (24 float4 = 96 VGPRs; block total 96 KB)

typedef __attribute__((ext_vector_type(8))) short short8;   // 8 bf16 = 4 VGPRs (MFMA A/B frag)
typedef __attribute__((ext_vector_type(4))) float f32x4;    // MFMA C/D frag

__global__ __launch_bounds__(256, 1) void ep_kernel(
    const int*   __restrict__ Nptr,    // [1]
    const int*   __restrict__ leaf,    // K x 64 (int32)
    const float* __restrict__ emb,     // K x 64 x 128
    const float* __restrict__ W1,      // 256 x 512
    const float* __restrict__ b1,      // 512
    const float* __restrict__ W2,      // 512 x 128
    const float* __restrict__ b2,      // 128
    const float* __restrict__ gum,     // K x 4096
    const float* __restrict__ u1,      // K
    const float* __restrict__ u2,      // K
    float* __restrict__ out)           // 17152 floats
{
    const int k    = blockIdx.x;
    const int tid  = threadIdx.x;
    const int lane = tid & 63;
    const int wid  = tid >> 6;

    __shared__ unsigned short EH[Tn * RS];   // bf16 hi of embeddings, 17408 B
    __shared__ unsigned short EL[Tn * RS];   // bf16 lo residual, 17408 B
    __shared__ float xs[256];        // concat(child1, child2)
    __shared__ float hsh[Hn];        // hidden layer
    __shared__ float buf[1024];      // MLP partials
    __shared__ float nI[Tn];         // squared norms (diag of Gram)
    __shared__ float sBest[4]; __shared__ int sIdx[4]; __shared__ float sW[4];
    __shared__ float sSum[4];
    __shared__ float sD1[4]; __shared__ float sD2[4];
    __shared__ int   sOnes;
    __shared__ int   fIdx; __shared__ float fW;
    __shared__ float embs[Dn];

    // wave -> 2x2 block of 16x16 G-tiles: wid 0..3 -> (itp,jtp); covers all 4x4 tiles
    const int itp  = wid >> 1;       // tile-row pair
    const int jtp  = wid & 1;        // tile-col pair
    const int lrow = lane & 15;      // fragment row/col within tile
    const int lq   = lane >> 4;      // k-quad (A/B) & row-quad (C/D)

    // L1 GEMV slice owned by this thread (also drives the W1 prefetch)
    const int j0    = 4 * (tid & 127);
    const int ih    = tid >> 7;
    const int ibase = ih * 128;
    const float* W1r = W1 + j0;

    // --- ones count (wave 0) ---
    if (tid < 64) {
        unsigned long long m = __ballot(leaf[k * Tn + tid] == 1);
        if (tid == 0) sOnes = __popcll(m);
    }

    // --- EARLY global loads: embeddings (8 f4) + gumbel (16) + W1 prefetch (24 f4).
    //     All issued before the Gram so their latency/stream hides under MFMA work.
    //     The W1 loads are argmax-independent; the compiler can't hoist them across
    //     the barriers itself, so we do it manually. ---
    float4 ev[8];
    {
        const float4* src = (const float4*)(emb + (size_t)k * Tn * Dn);
        #pragma unroll
        for (int it = 0; it < 8; ++it) ev[it] = src[tid + it * 256];
    }
    float gv[16];
    {
        const float* gk = gum + (size_t)k * (Tn * Tn);
        #pragma unroll
        for (int a = 0; a < 2; ++a)
            #pragma unroll
            for (int b = 0; b < 2; ++b) {
                int it = 2 * itp + a, jt = 2 * jtp + b;
                int col = jt * 16 + lrow;
                #pragma unroll
                for (int r = 0; r < 4; ++r) {
                    int row = it * 16 + lq * 4 + r;
                    gv[(a * 2 + b) * 4 + r] = gk[row * Tn + col];
                }
            }
    }
    float4 wpre[NPRE];
    #pragma unroll
    for (int p = 0; p < NPRE; ++p)
        wpre[p] = *(const float4*)&W1r[(size_t)(ibase + p) * Hn];

    // --- pack split-bf16 embeddings into LDS (e = hi + lo, |err| <= 2^-16|e|) ---
    #pragma unroll
    for (int it = 0; it < 8; ++it) {
        int f4 = tid + it * 256;
        int i  = f4 >> 5;
        int d0 = (f4 & 31) << 2;
        float4 v = ev[it];
        unsigned short hx = __float_as_uint(v.x) >> 16, hy = __float_as_uint(v.y) >> 16,
                       hz = __float_as_uint(v.z) >> 16, hw = __float_as_uint(v.w) >> 16;
        float rx = v.x - __uint_as_float((unsigned int)hx << 16);
        float ry = v.y - __uint_as_float((unsigned int)hy << 16);
        float rz = v.z - __uint_as_float((unsigned int)hz << 16);
        float rw = v.w - __uint_as_float((unsigned int)hw << 16);
        unsigned short lx = __float_as_uint(rx) >> 16, ly = __float_as_uint(ry) >> 16,
                       lz = __float_as_uint(rz) >> 16, lw = __float_as_uint(rw) >> 16;
        *(ushort4*)&EH[i * RS + d0] = make_ushort4(hx, hy, hz, hw);
        *(ushort4*)&EL[i * RS + d0] = make_ushort4(lx, ly, lz, lw);
    }
    __syncthreads();

    // --- MFMA Gram: G = Ehi.Ehi^T + Ehi.Elo^T + Elo.Ehi^T (fp32-accurate) ---
    f32x4 acc[2][2] = {};
    const int ka = lq * 8;
    #pragma unroll
    for (int ks = 0; ks < 4; ++ks) {
        int kb  = ks * 32 + ka;
        int ra0 = ((2 * itp + 0) * 16 + lrow) * RS + kb;
        int ra1 = ra0 + 16 * RS;
        int rb0 = ((2 * jtp + 0) * 16 + lrow) * RS + kb;
        int rb1 = rb0 + 16 * RS;
        short8 ah0 = *(const short8*)&EH[ra0], ah1 = *(const short8*)&EH[ra1];
        short8 al0 = *(const short8*)&EL[ra0], al1 = *(const short8*)&EL[ra1];
        short8 bh0 = *(const short8*)&EH[rb0], bh1 = *(const short8*)&EH[rb1];
        short8 bl0 = *(const short8*)&EL[rb0], bl1 = *(const short8*)&EL[rb1];
        acc[0][0] = __builtin_amdgcn_mfma_f32_16x16x32_bf16(ah0, bh0, acc[0][0], 0, 0, 0);
        acc[0][1] = __builtin_amdgcn_mfma_f32_16x16x32_bf16(ah0, bh1, acc[0][1], 0, 0, 0);
        acc[1][0] = __builtin_amdgcn_mfma_f32_16x16x32_bf16(ah1, bh0, acc[1][0], 0, 0, 0);
        acc[1][1] = __builtin_amdgcn_mfma_f32_16x16x32_bf16(ah1, bh1, acc[1][1], 0, 0, 0);
        acc[0][0] = __builtin_amdgcn_mfma_f32_16x16x32_bf16(ah0, bl0, acc[0][0], 0, 0, 0);
        acc[0][1] = __builtin_amdgcn_mfma_f32_16x16x32_bf16(ah0, bl1, acc[0][1], 0, 0, 0);
        acc[1][0] = __builtin_amdgcn_mfma_f32_16x16x32_bf16(ah1, bl0, acc[1][0], 0, 0, 0);
        acc[1][1] = __builtin_amdgcn_mfma_f32_16x16x32_bf16(ah1, bl1, acc[1][1], 0, 0, 0);
        acc[0][0] = __builtin_amdgcn_mfma_f32_16x16x32_bf16(al0, bh0, acc[0][0], 0, 0, 0);
        acc[0][1] = __builtin_amdgcn_mfma_f32_16x16x32_bf16(al0, bh1, acc[0][1], 0, 0, 0);
        acc[1][0] = __builtin_amdgcn_mfma_f32_16x16x32_bf16(al1, bh0, acc[1][0], 0, 0, 0);
        acc[1][1] = __builtin_amdgcn_mfma_f32_16x16x32_bf16(al1, bh1, acc[1][1], 0, 0, 0);
    }

    // --- norms from diagonal tiles ---
    if (itp == jtp) {
        #pragma unroll
        for (int a = 0; a < 2; ++a) {
            if ((lrow >> 2) == lq) {
                int c = lrow;
                int t = 2 * itp + a;
                f32x4 v = acc[a][a];
                int   s = c & 3;
                float val = (s == 0) ? v.x : (s == 1) ? v.y : (s == 2) ? v.z : v.w;
                nI[t * 16 + c] = val;
            }
        }
    }
    __syncthreads();

    // --- merge log-weights + argmax(w+g) + direct expsum ---
    float es = 0.0f, best = -INFINITY, bestW = 0.0f;
    int   bestIdx = 0;
    #pragma unroll
    for (int a = 0; a < 2; ++a)
        #pragma unroll
        for (int b = 0; b < 2; ++b) {
            int it = 2 * itp + a, jt = 2 * jtp + b;
            int col = jt * 16 + lrow;
            float njc = nI[col];
            f32x4 v = acc[a][b];
            float gvals[4] = {v.x, v.y, v.z, v.w};
            #pragma unroll
            for (int r = 0; r < 4; ++r) {
                int row = it * 16 + lq * 4 + r;
                float pd2 = nI[row] + njc - 2.0f * gvals[r];
                pd2 = fmaxf(pd2, 0.0f) + 1e-12f;
                float wv = (row == col) ? -INFINITY : -sqrtf(pd2);
                es += expf(wv);
                float wg = wv + gv[(a * 2 + b) * 4 + r];
                int idx = row * Tn + col;
                if (wg > best || (wg == best && idx < bestIdx)) {
                    best = wg; bestIdx = idx; bestW = wv;
                }
            }
        }

    // --- single fused block reduction: argmax triple + expsum ---
    #pragma unroll
    for (int off = 32; off > 0; off >>= 1) {
        float ob = __shfl_down(best, off);
        int   oi = __shfl_down(bestIdx, off);
        float ow = __shfl_down(bestW, off);
        float oe = __shfl_down(es, off);
        if (ob > best || (ob == best && oi < bestIdx)) { best = ob; bestIdx = oi; bestW = ow; }
        es += oe;
    }
    if (lane == 0) { sBest[wid] = best; sIdx[wid] = bestIdx; sW[wid] = bestW; sSum[wid] = es; }
    __syncthreads();
    if (tid == 0) {
        best = sBest[0]; bestIdx = sIdx[0]; bestW = sW[0];
        #pragma unroll
        for (int q = 1; q < 4; ++q) {
            if (sBest[q] > best || (sBest[q] == best && sIdx[q] < bestIdx)) {
                best = sBest[q]; bestIdx = sIdx[q]; bestW = sW[q];
            }
        }
        fIdx = bestIdx; fW = bestW;
    }
    __syncthreads();

    const int i1 = fIdx >> 6;
    const int i2 = fIdx & 63;

    // --- gather children into xs = concat(c1, c2), reconstructed hi+lo ---
    {
        int d  = tid & 127;
        int ii = (tid < 128) ? i1 : i2;
        float hi = __uint_as_float((unsigned int)EH[ii * RS + d] << 16);
        float lo = __uint_as_float((unsigned int)EL[ii * RS + d] << 16);
        xs[tid] = hi + lo;
    }
    __syncthreads();

    // --- MLP layer 1: thread owns 4 cols over one i-half; first NPRE rows from
    //     the prefetch registers (same FMA order -> bit-identical), rest global ---
    {
        float a0 = 0.0f, a1 = 0.0f, a2 = 0.0f, a3 = 0.0f;
        #pragma unroll
        for (int i = 0; i < NPRE; i += 4) {
            float4 x  = *(const float4*)&xs[ibase + i];
            float4 w0 = wpre[i + 0];
            float4 w1 = wpre[i + 1];
            float4 w2 = wpre[i + 2];
            float4 w3 = wpre[i + 3];
            a0 += x.x * w0.x + x.y * w1.x + x.z * w2.x + x.w * w3.x;
            a1 += x.x * w0.y + x.y * w1.y + x.z * w2.y + x.w * w3.y;
            a2 += x.x * w0.z + x.y * w1.z + x.z * w2.z + x.w * w3.z;
            a3 += x.x * w0.w + x.y * w1.w + x.z * w2.w + x.w * w3.w;
        }
        #pragma unroll 4
        for (int i = ibase + NPRE; i < ibase + 128; i += 4) {
            float4 x  = *(const float4*)&xs[i];
            float4 w0 = *(const float4*)&W1r[(size_t)(i + 0) * Hn];
            float4 w1 = *(const float4*)&W1r[(size_t)(i + 1) * Hn];
            float4 w2 = *(const float4*)&W1r[(size_t)(i + 2) * Hn];
            float4 w3 = *(const float4*)&W1r[(size_t)(i + 3) * Hn];
            a0 += x.x * w0.x + x.y * w1.x + x.z * w2.x + x.w * w3.x;
            a1 += x.x * w0.y + x.y * w1.y + x.z * w2.y + x.w * w3.y;
            a2 += x.x * w0.z + x.y * w1.z + x.z * w2.z + x.w * w3.z;
            a3 += x.x * w0.w + x.y * w1.w + x.z * w2.w + x.w * w3.w;
        }
        *(float4*)&buf[ih * Hn + j0] = make_float4(a0, a1, a2, a3);
    }
    __syncthreads();
    // combine i-halves + bias + relu
    {
        int j = tid;
        hsh[j] = fmaxf(buf[j] + buf[Hn + j] + b1[j], 0.0f);
        j = tid + 256;
        hsh[j] = fmaxf(buf[j] + buf[Hn + j] + b1[j], 0.0f);
    }
    __syncthreads();

    // --- MLP layer 2: thread owns 4 dd-cols over a 64-wide j-slice (8-way split) ---
    {
        const int jh  = tid >> 5;          // 0..7
        const int dd4 = 4 * (tid & 31);    // 0..124
        float a0 = 0.0f, a1 = 0.0f, a2 = 0.0f, a3 = 0.0f;
        const int jbase = jh * 64;
        #pragma unroll 4
        for (int j = jbase; j < jbase + 64; j += 4) {
            float4 h4 = *(const float4*)&hsh[j];
            float4 w0 = *(const float4*)&W2[(size_t)(j + 0) * Dn + dd4];
            float4 w1 = *(const float4*)&W2[(size_t)(j + 1) * Dn + dd4];
            float4 w2 = *(const float4*)&W2[(size_t)(j + 2) * Dn + dd4];
            float4 w3 = *(const float4*)&W2[(size_t)(j + 3) * Dn + dd4];
            a0 += h4.x * w0.x + h4.y * w1.x + h4.z * w2.x + h4.w * w3.x;
            a1 += h4.x * w0.y + h4.y * w1.y + h4.z * w2.y + h4.w * w3.y;
            a2 += h4.x * w0.z + h4.y * w1.z + h4.z * w2.z + h4.w * w3.z;
            a3 += h4.x * w0.w + h4.y * w1.w + h4.z * w2.w + h4.w * w3.w;
        }
        *(float4*)&buf[jh * Dn + dd4] = make_float4(a0, a1, a2, a3);
    }
    __syncthreads();
    if (tid < 128) {
        float e = b2[tid];
        #pragma unroll
        for (int q = 0; q < 8; ++q) e += buf[q * Dn + tid];
        embs[tid] = e;
        out[4 * Kp + k * Dn + tid] = e;   // embedding output at offset 512
    }
    __syncthreads();

    // --- branch distances d1, d2 ---
    float v1 = 0.0f, v2 = 0.0f;
    if (tid < 128) {
        float e  = embs[tid];
        float q1 = xs[tid] - e;        v1 = q1 * q1;
        float q2 = xs[128 + tid] - e;  v2 = q2 * q2;
    }
    #pragma unroll
    for (int off = 32; off > 0; off >>= 1) {
        v1 += __shfl_down(v1, off);
        v2 += __shfl_down(v2, off);
    }
    if (lane == 0) { sD1[wid] = v1; sD2[wid] = v2; }
    __syncthreads();

    // --- scalar epilogue (thread 0) ---
    if (tid == 0) {
        float s1 = sD1[0] + sD1[1] + sD1[2] + sD1[3];
        float s2 = sD2[0] + sD2[1] + sD2[2] + sD2[3];
        float d1 = sqrtf(s1 + 1e-12f);
        float d2 = sqrtf(s2 + 1e-12f);
        float rate1 = 1.0f / (d1 + 1e-4f);
        float rate2 = 1.0f / (d2 + 1e-4f);
        float branch1 = -(1.0f / rate1) * logf(u1[k]);
        float branch2 = -(1.0f / rate2) * logf(u2[k]);
        float lbp1 = logf(rate1) - rate1 * branch1;
        float lbp2 = logf(rate2) - rate2 * branch2;
        float ssum = sSum[0] + sSum[1] + sSum[2] + sSum[3];
        float lse  = logf(ssum);                          // direct-sum logsumexp
        float lmp  = fW + 0.69314718055994531f - lse;     // + log(2)
        float lvp  = lmp + lbp1 + lbp2;
        int lc1 = leaf[k * Tn + i1];
        int lc2 = leaf[k * Tn + i2];
        int ones = sOnes - (lc1 == 1 ? 1 : 0) - (lc2 == 1 ? 1 : 0);
        float lvm = logf((float)(Nptr[0] - ones));

        out[k]                         = (float)i1;
        out[Kp + k]                    = (float)i2;
        out[2 * Kp + k]                = branch1;
        out[3 * Kp + k]                = branch2;
        out[4 * Kp + Kp * Dn + k]      = lvp;   // offset 16896
        out[4 * Kp + Kp * Dn + Kp + k] = lvm;   // offset 17024
    }
}

extern "C" void kernel_launch(void* const* d_in, const int* in_sizes, int n_in,
                              void* d_out, int out_size, void* d_ws, size_t ws_size,
                              hipStream_t stream) {
    const int*   Nptr = (const int*)  d_in[0];
    const int*   leaf = (const int*)  d_in[1];
    const float* emb  = (const float*)d_in[2];
    // d_in[3] log_felsensteins, d_in[4] site_positions: unused by reference
    const float* W1   = (const float*)d_in[5];
    const float* b1   = (const float*)d_in[6];
    const float* W2   = (const float*)d_in[7];
    const float* b2   = (const float*)d_in[8];
    const float* gum  = (const float*)d_in[9];
    const float* u1   = (const float*)d_in[10];
    const float* u2   = (const float*)d_in[11];
    float* out = (float*)d_out;

    ep_kernel<<<Kp, 256, 0, stream>>>(Nptr, leaf, emb, W1, b1, W2, b2, gum, u1, u2, out);
}

// Round 8
// 126.507 us; speedup vs baseline: 1.1179x; 1.0046x over previous
//
#include <hip/hip_runtime.h>
#include <math.h>

// Problem constants (match reference)
#define Kp 128
#define Tn 64
#define Dn 128
#define Hn 512
#define RS 136   // ushort row stride for bf16 E rows: 272 B (16B-aligned), +4 banks/row

typedef __attribute__((ext_vector_type(8))) short short8;   // 8 bf16 = 4 VGPRs (MFMA A/B frag)
typedef __attribute__((ext_vector_type(4))) float f32x4;    // MFMA C/D frag

// R5 skeleton widened to 512 threads: waves 0-3 own the (cheap) Gram/argmax
// phase; waves 4-7 idle through it and join for the latency-bound MLP weight
// stream, doubling outstanding VMEM requests (kernel is latency-bound at 3%
// VALUBusy / 145 GB/s — R7 counters).
__global__ __launch_bounds__(512, 1) void ep_kernel(
    const int*   __restrict__ Nptr,    // [1]
    const int*   __restrict__ leaf,    // K x 64 (int32)
    const float* __restrict__ emb,     // K x 64 x 128
    const float* __restrict__ W1,      // 256 x 512
    const float* __restrict__ b1,      // 512
    const float* __restrict__ W2,      // 512 x 128
    const float* __restrict__ b2,      // 128
    const float* __restrict__ gum,     // K x 4096
    const float* __restrict__ u1,      // K
    const float* __restrict__ u2,      // K
    float* __restrict__ out)           // 17152 floats
{
    const int k    = blockIdx.x;
    const int tid  = threadIdx.x;
    const int lane = tid & 63;
    const int wid  = tid >> 6;          // 0..7

    __shared__ unsigned short EH[Tn * RS];   // bf16 hi of embeddings, 17408 B
    __shared__ unsigned short EL[Tn * RS];   // bf16 lo residual, 17408 B
    __shared__ float xs[256];        // concat(child1, child2)
    __shared__ float hsh[Hn];        // hidden layer
    __shared__ float buf[2112];      // MLP partials (L1: 4x516, L2: 16x132)
    __shared__ float nI[Tn];         // squared norms (diag of Gram)
    __shared__ float sBest[8]; __shared__ int sIdx[8]; __shared__ float sW[8];
    __shared__ float sSum[8];
    __shared__ float sD1[2]; __shared__ float sD2[2];
    __shared__ int   sOnes;
    __shared__ int   fIdx; __shared__ float fW;
    __shared__ float embs[Dn];

    // waves 0-3 -> 2x2 block of 16x16 G-tiles (covers all 4x4 tiles)
    const bool gw   = (wid < 4);
    const int itp   = (wid >> 1) & 1;   // tile-row pair (valid for gw)
    const int jtp   = wid & 1;          // tile-col pair
    const int lrow  = lane & 15;        // fragment row/col within tile
    const int lq    = lane >> 4;        // k-quad (A/B) & row-quad (C/D)

    // --- ones count (wave 0) ---
    if (tid < 64) {
        unsigned long long m = __ballot(leaf[k * Tn + tid] == 1);
        if (tid == 0) sOnes = __popcll(m);
    }

    // --- EARLY global loads: embeddings (4 f4 each) + gumbel (16, waves 0-3) ---
    float4 ev[4];
    {
        const float4* src = (const float4*)(emb + (size_t)k * Tn * Dn);
        #pragma unroll
        for (int it = 0; it < 4; ++it) ev[it] = src[tid + it * 512];
    }
    float gv[16];
    if (gw) {
        const float* gk = gum + (size_t)k * (Tn * Tn);
        #pragma unroll
        for (int a = 0; a < 2; ++a)
            #pragma unroll
            for (int b = 0; b < 2; ++b) {
                int it = 2 * itp + a, jt = 2 * jtp + b;
                int col = jt * 16 + lrow;
                #pragma unroll
                for (int r = 0; r < 4; ++r) {
                    int row = it * 16 + lq * 4 + r;
                    gv[(a * 2 + b) * 4 + r] = gk[row * Tn + col];
                }
            }
    }

    // --- pack split-bf16 embeddings into LDS (e = hi + lo, |err| <= 2^-16|e|) ---
    #pragma unroll
    for (int it = 0; it < 4; ++it) {
        int f4 = tid + it * 512;
        int i  = f4 >> 5;
        int d0 = (f4 & 31) << 2;
        float4 v = ev[it];
        unsigned short hx = __float_as_uint(v.x) >> 16, hy = __float_as_uint(v.y) >> 16,
                       hz = __float_as_uint(v.z) >> 16, hw = __float_as_uint(v.w) >> 16;
        float rx = v.x - __uint_as_float((unsigned int)hx << 16);
        float ry = v.y - __uint_as_float((unsigned int)hy << 16);
        float rz = v.z - __uint_as_float((unsigned int)hz << 16);
        float rw = v.w - __uint_as_float((unsigned int)hw << 16);
        unsigned short lx = __float_as_uint(rx) >> 16, ly = __float_as_uint(ry) >> 16,
                       lz = __float_as_uint(rz) >> 16, lw = __float_as_uint(rw) >> 16;
        *(ushort4*)&EH[i * RS + d0] = make_ushort4(hx, hy, hz, hw);
        *(ushort4*)&EL[i * RS + d0] = make_ushort4(lx, ly, lz, lw);
    }
    __syncthreads();

    // --- MFMA Gram (waves 0-3): G = Ehi.Ehi^T + Ehi.Elo^T + Elo.Ehi^T ---
    f32x4 acc[2][2] = {};
    if (gw) {
        const int ka = lq * 8;
        #pragma unroll
        for (int ks = 0; ks < 4; ++ks) {
            int kb  = ks * 32 + ka;
            int ra0 = ((2 * itp + 0) * 16 + lrow) * RS + kb;
            int ra1 = ra0 + 16 * RS;
            int rb0 = ((2 * jtp + 0) * 16 + lrow) * RS + kb;
            int rb1 = rb0 + 16 * RS;
            short8 ah0 = *(const short8*)&EH[ra0], ah1 = *(const short8*)&EH[ra1];
            short8 al0 = *(const short8*)&EL[ra0], al1 = *(const short8*)&EL[ra1];
            short8 bh0 = *(const short8*)&EH[rb0], bh1 = *(const short8*)&EH[rb1];
            short8 bl0 = *(const short8*)&EL[rb0], bl1 = *(const short8*)&EL[rb1];
            acc[0][0] = __builtin_amdgcn_mfma_f32_16x16x32_bf16(ah0, bh0, acc[0][0], 0, 0, 0);
            acc[0][1] = __builtin_amdgcn_mfma_f32_16x16x32_bf16(ah0, bh1, acc[0][1], 0, 0, 0);
            acc[1][0] = __builtin_amdgcn_mfma_f32_16x16x32_bf16(ah1, bh0, acc[1][0], 0, 0, 0);
            acc[1][1] = __builtin_amdgcn_mfma_f32_16x16x32_bf16(ah1, bh1, acc[1][1], 0, 0, 0);
            acc[0][0] = __builtin_amdgcn_mfma_f32_16x16x32_bf16(ah0, bl0, acc[0][0], 0, 0, 0);
            acc[0][1] = __builtin_amdgcn_mfma_f32_16x16x32_bf16(ah0, bl1, acc[0][1], 0, 0, 0);
            acc[1][0] = __builtin_amdgcn_mfma_f32_16x16x32_bf16(ah1, bl0, acc[1][0], 0, 0, 0);
            acc[1][1] = __builtin_amdgcn_mfma_f32_16x16x32_bf16(ah1, bl1, acc[1][1], 0, 0, 0);
            acc[0][0] = __builtin_amdgcn_mfma_f32_16x16x32_bf16(al0, bh0, acc[0][0], 0, 0, 0);
            acc[0][1] = __builtin_amdgcn_mfma_f32_16x16x32_bf16(al0, bh1, acc[0][1], 0, 0, 0);
            acc[1][0] = __builtin_amdgcn_mfma_f32_16x16x32_bf16(al1, bh0, acc[1][0], 0, 0, 0);
            acc[1][1] = __builtin_amdgcn_mfma_f32_16x16x32_bf16(al1, bh1, acc[1][1], 0, 0, 0);
        }

        // --- norms from diagonal tiles ---
        if (itp == jtp) {
            #pragma unroll
            for (int a = 0; a < 2; ++a) {
                if ((lrow >> 2) == lq) {
                    int c = lrow;
                    int t = 2 * itp + a;
                    f32x4 v = acc[a][a];
                    int   s = c & 3;
                    float val = (s == 0) ? v.x : (s == 1) ? v.y : (s == 2) ? v.z : v.w;
                    nI[t * 16 + c] = val;
                }
            }
        }
    }
    __syncthreads();

    // --- merge log-weights + argmax(w+g) + direct expsum (waves 0-3) ---
    float es = 0.0f, best = -INFINITY, bestW = 0.0f;
    int   bestIdx = 0;
    if (gw) {
        #pragma unroll
        for (int a = 0; a < 2; ++a)
            #pragma unroll
            for (int b = 0; b < 2; ++b) {
                int it = 2 * itp + a, jt = 2 * jtp + b;
                int col = jt * 16 + lrow;
                float njc = nI[col];
                f32x4 v = acc[a][b];
                float gvals[4] = {v.x, v.y, v.z, v.w};
                #pragma unroll
                for (int r = 0; r < 4; ++r) {
                    int row = it * 16 + lq * 4 + r;
                    float pd2 = nI[row] + njc - 2.0f * gvals[r];
                    pd2 = fmaxf(pd2, 0.0f) + 1e-12f;
                    float wv = (row == col) ? -INFINITY : -sqrtf(pd2);
                    es += expf(wv);
                    float wg = wv + gv[(a * 2 + b) * 4 + r];
                    int idx = row * Tn + col;
                    if (wg > best || (wg == best && idx < bestIdx)) {
                        best = wg; bestIdx = idx; bestW = wv;
                    }
                }
            }
    }

    // --- fused block reduction (8 waves; idle waves carry identities) ---
    #pragma unroll
    for (int off = 32; off > 0; off >>= 1) {
        float ob = __shfl_down(best, off);
        int   oi = __shfl_down(bestIdx, off);
        float ow = __shfl_down(bestW, off);
        float oe = __shfl_down(es, off);
        if (ob > best || (ob == best && oi < bestIdx)) { best = ob; bestIdx = oi; bestW = ow; }
        es += oe;
    }
    if (lane == 0) { sBest[wid] = best; sIdx[wid] = bestIdx; sW[wid] = bestW; sSum[wid] = es; }
    __syncthreads();
    if (tid == 0) {
        best = sBest[0]; bestIdx = sIdx[0]; bestW = sW[0];
        #pragma unroll
        for (int q = 1; q < 8; ++q) {
            if (sBest[q] > best || (sBest[q] == best && sIdx[q] < bestIdx)) {
                best = sBest[q]; bestIdx = sIdx[q]; bestW = sW[q];
            }
        }
        fIdx = bestIdx; fW = bestW;
    }
    __syncthreads();

    const int i1 = fIdx >> 6;
    const int i2 = fIdx & 63;

    // --- gather children into xs = concat(c1, c2), reconstructed hi+lo ---
    if (tid < 256) {
        int d  = tid & 127;
        int ii = (tid < 128) ? i1 : i2;
        float hi = __uint_as_float((unsigned int)EH[ii * RS + d] << 16);
        float lo = __uint_as_float((unsigned int)EL[ii * RS + d] << 16);
        xs[tid] = hi + lo;
    }
    __syncthreads();

    // --- MLP layer 1: thread owns 4 cols over an i-quarter (4-way split, 512 thr) ---
    {
        const int j0 = 4 * (tid & 127);
        const int ih = tid >> 7;               // 0..3
        const float* W1r = W1 + j0;
        float4 a = {0, 0, 0, 0};
        const int ib = ih * 64;
        #pragma unroll 4
        for (int i = ib; i < ib + 64; i += 4) {
            float4 x  = *(const float4*)&xs[i];
            float4 w0 = *(const float4*)&W1r[(size_t)(i + 0) * Hn];
            float4 w1 = *(const float4*)&W1r[(size_t)(i + 1) * Hn];
            float4 w2 = *(const float4*)&W1r[(size_t)(i + 2) * Hn];
            float4 w3 = *(const float4*)&W1r[(size_t)(i + 3) * Hn];
            a.x += x.x * w0.x + x.y * w1.x + x.z * w2.x + x.w * w3.x;
            a.y += x.x * w0.y + x.y * w1.y + x.z * w2.y + x.w * w3.y;
            a.z += x.x * w0.z + x.y * w1.z + x.z * w2.z + x.w * w3.z;
            a.w += x.x * w0.w + x.y * w1.w + x.z * w2.w + x.w * w3.w;
        }
        *(float4*)&buf[ih * 516 + j0] = a;   // stride 516: %32==4 -> conflict-free combine
    }
    __syncthreads();
    hsh[tid] = fmaxf(b1[tid] + buf[tid] + buf[516 + tid]
                     + buf[1032 + tid] + buf[1548 + tid], 0.0f);
    __syncthreads();

    // --- MLP layer 2: thread owns 4 d-cols over a 32-wide j-slice (16-way split) ---
    {
        const int jh  = tid >> 5;          // 0..15
        const int dd4 = 4 * (tid & 31);    // 0..124
        float4 a = {0, 0, 0, 0};
        const int jb = jh * 32;
        #pragma unroll 4
        for (int j = jb; j < jb + 32; j += 4) {
            float4 h4 = *(const float4*)&hsh[j];
            float4 w0 = *(const float4*)&W2[(size_t)(j + 0) * Dn + dd4];
            float4 w1 = *(const float4*)&W2[(size_t)(j + 1) * Dn + dd4];
            float4 w2 = *(const float4*)&W2[(size_t)(j + 2) * Dn + dd4];
            float4 w3 = *(const float4*)&W2[(size_t)(j + 3) * Dn + dd4];
            a.x += h4.x * w0.x + h4.y * w1.x + h4.z * w2.x + h4.w * w3.x;
            a.y += h4.x * w0.y + h4.y * w1.y + h4.z * w2.y + h4.w * w3.y;
            a.z += h4.x * w0.z + h4.y * w1.z + h4.z * w2.z + h4.w * w3.z;
            a.w += h4.x * w0.w + h4.y * w1.w + h4.z * w2.w + h4.w * w3.w;
        }
        *(float4*)&buf[jh * 132 + dd4] = a;    // stride 132: %32==4 -> conflict-free combine
    }
    __syncthreads();
    if (tid < 128) {
        float e = b2[tid];
        #pragma unroll
        for (int p = 0; p < 16; ++p) e += buf[p * 132 + tid];
        embs[tid] = e;
        out[4 * Kp + k * Dn + tid] = e;   // embedding output at offset 512
    }
    __syncthreads();

    // --- branch distances d1, d2 (waves 0-1) ---
    if (tid < 128) {
        float e  = embs[tid];
        float q1 = xs[tid] - e;        float v1 = q1 * q1;
        float q2 = xs[128 + tid] - e;  float v2 = q2 * q2;
        #pragma unroll
        for (int off = 32; off > 0; off >>= 1) {
            v1 += __shfl_down(v1, off);
            v2 += __shfl_down(v2, off);
        }
        if (lane == 0) { sD1[wid] = v1; sD2[wid] = v2; }
    }
    __syncthreads();

    // --- scalar epilogue (thread 0) ---
    if (tid == 0) {
        float s1 = sD1[0] + sD1[1];
        float s2 = sD2[0] + sD2[1];
        float d1 = sqrtf(s1 + 1e-12f);
        float d2 = sqrtf(s2 + 1e-12f);
        float rate1 = 1.0f / (d1 + 1e-4f);
        float rate2 = 1.0f / (d2 + 1e-4f);
        float branch1 = -(1.0f / rate1) * logf(u1[k]);
        float branch2 = -(1.0f / rate2) * logf(u2[k]);
        float lbp1 = logf(rate1) - rate1 * branch1;
        float lbp2 = logf(rate2) - rate2 * branch2;
        float ssum = sSum[0] + sSum[1] + sSum[2] + sSum[3]
                   + sSum[4] + sSum[5] + sSum[6] + sSum[7];
        float lse  = logf(ssum);                          // direct-sum logsumexp
        float lmp  = fW + 0.69314718055994531f - lse;     // + log(2)
        float lvp  = lmp + lbp1 + lbp2;
        int lc1 = leaf[k * Tn + i1];
        int lc2 = leaf[k * Tn + i2];
        int ones = sOnes - (lc1 == 1 ? 1 : 0) - (lc2 == 1 ? 1 : 0);
        float lvm = logf((float)(Nptr[0] - ones));

        out[k]                         = (float)i1;
        out[Kp + k]                    = (float)i2;
        out[2 * Kp + k]                = branch1;
        out[3 * Kp + k]                = branch2;
        out[4 * Kp + Kp * Dn + k]      = lvp;   // offset 16896
        out[4 * Kp + Kp * Dn + Kp + k] = lvm;   // offset 17024
    }
}

extern "C" void kernel_launch(void* const* d_in, const int* in_sizes, int n_in,
                              void* d_out, int out_size, void* d_ws, size_t ws_size,
                              hipStream_t stream) {
    const int*   Nptr = (const int*)  d_in[0];
    const int*   leaf = (const int*)  d_in[1];
    const float* emb  = (const float*)d_in[2];
    // d_in[3] log_felsensteins, d_in[4] site_positions: unused by reference
    const float* W1   = (const float*)d_in[5];
    const float* b1   = (const float*)d_in[6];
    const float* W2   = (const float*)d_in[7];
    const float* b2   = (const float*)d_in[8];
    const float* gum  = (const float*)d_in[9];
    const float* u1   = (const float*)d_in[10];
    const float* u2   = (const float*)d_in[11];
    float* out = (float*)d_out;

    ep_kernel<<<Kp, 512, 0, stream>>>(Nptr, leaf, emb, W1, b1, W2, b2, gum, u1, u2, out);
}